// Round 10
// baseline (171.593 us; speedup 1.0000x reference)
//
#include <hip/hip_runtime.h>
#include <hip/hip_bf16.h>

// y = (spikes @ V) @ U^T
// spikes: [4096, 16384] f32, V: [16384, 32] f32, U: [16384, 32] f32
// y: [4096, 16384] f32 (268 MB). Mask inputs are dead in the reference.
//
// r10: r9 structure VERBATIM except ykernel stores are NON-TEMPORAL.
// Theory: dirty y lines parked in L3 (invisible to TCC counters) force
// DRAM read/writeback interleaving during zpart -> bus-turnaround throttle
// (~2.3 TB/s reads). NT y-stores keep L3 clean; spikes loads stay cached
// (r7 regressed because it ALSO made spikes loads NT - confounded test).

#define B_DIM 4096
#define NPRE  16384
#define NPOST 16384
#define RDIM  32

#define ROWS   16
#define TILEK  512                    // k per tile (2 KB per row)
#define NTILE  (NPRE / TILEK)         // 32
#define ROWB   2064                   // LDS bytes per row (2048 + 16 pad -> 2-way-free banks)
#define TBUF   (ROWS * ROWB)          // 33024 B per buffer

typedef __attribute__((ext_vector_type(8))) short short8;   // 8 bf16
typedef __attribute__((ext_vector_type(4))) float f32x4;
typedef const __attribute__((address_space(1))) void GAS;
typedef __attribute__((address_space(3))) void LAS;

static __device__ __forceinline__ unsigned pack_bf2(float lo, float hi) {
    union { __hip_bfloat162 h; unsigned u; } c;
    c.h = __float22bfloat162_rn(make_float2(lo, hi));   // v_cvt_pk_bf16_f32
    return c.u;
}

// ---- V packing (proven r4): vpack[((kt*2+half)*64 + lane)*8 + e]
//      = bf16(V[kt*32 + (lane>>4)*8 + e][half*16 + (lane&15)])
__global__ void vpack_kernel(const float* __restrict__ V, short* __restrict__ vpack)
{
    const int tid  = blockIdx.x * 256 + threadIdx.x;   // 65536
    const int lane = tid & 63;
    const int half = (tid >> 6) & 1;
    const int kt   = tid >> 7;
    const int n    = half * 16 + (lane & 15);
    const int k0   = kt * 32 + (lane >> 4) * 8;
    union { short8 s; short el[8]; } f;
    #pragma unroll
    for (int e = 0; e < 8; ++e) {
        union { __hip_bfloat16 h; short s; } c;
        c.h = __float2bfloat16(V[(size_t)(k0 + e) * RDIM + n]);
        f.el[e] = c.s;
    }
    *reinterpret_cast<short8*>(vpack + (size_t)tid * 8) = f.s;
}

// ---- phase A: block = 16 rows x full K. Wave w streams rows 2w,2w+1
// linearly via DMA; waves split each tile's 16 k-steps as {2w, 2w+1}.
__global__ __launch_bounds__(512) void zpart_kernel(
    const float* __restrict__ spikes, const short* __restrict__ vpack,
    float* __restrict__ z)
{
    __shared__ char smem[2 * TBUF];    // 66 KB

    const int tid  = threadIdx.x;
    const int lane = tid & 63;
    const int w    = tid >> 6;         // wave 0..7
    const int brow = blockIdx.x * ROWS;

    const int m  = lane & 15;          // fragment batch-row
    const int kg = lane >> 4;          // k-group

    // DMA descriptors: instr q covers row 2w+(q>>1), KB half kp=q&1
    const float* g[4];
    int ldst[4];
    #pragma unroll
    for (int q = 0; q < 4; ++q) {
        const int row = 2 * w + (q >> 1);
        const int kp  = q & 1;
        g[q]   = spikes + (size_t)(brow + row) * NPRE + kp * 256 + lane * 4;
        ldst[q] = row * ROWB + kp * 1024;
    }

    f32x4 acc0 = {0.f, 0.f, 0.f, 0.f};
    f32x4 acc1 = {0.f, 0.f, 0.f, 0.f};

    // prologue: tile 0 -> buf 0
    #pragma unroll
    for (int q = 0; q < 4; ++q)
        __builtin_amdgcn_global_load_lds((GAS*)g[q], (LAS*)(smem + ldst[q]), 16, 0, 0);

    #pragma unroll 1
    for (int t = 0; t < NTILE; ++t) {
        __syncthreads();               // drains vmcnt: tile t resident in buf t&1

        if (t + 1 < NTILE) {           // prefetch whole next tile (32 KB in flight)
            char* nb = smem + ((t + 1) & 1) * TBUF;
            #pragma unroll
            for (int q = 0; q < 4; ++q)
                __builtin_amdgcn_global_load_lds(
                    (GAS*)(g[q] + (size_t)(t + 1) * TILEK),
                    (LAS*)(nb + ldst[q]), 16, 0, 0);
        }

        const char* sb = smem + (t & 1) * TBUF + m * ROWB;
        #pragma unroll
        for (int p = 0; p < 2; ++p) {
            const int ks = 2 * w + p;                  // tile-local k-step
            const int kt = t * 16 + ks;                // global k-step
            const short* bt = vpack + (size_t)kt * 1024 + lane * 8;
            const short8 b0 = *reinterpret_cast<const short8*>(bt);
            const short8 b1 = *reinterpret_cast<const short8*>(bt + 512);
            const f32x4 al = *reinterpret_cast<const f32x4*>(sb + ks * 128 + kg * 32);
            const f32x4 ah = *reinterpret_cast<const f32x4*>(sb + ks * 128 + kg * 32 + 16);
            union { short8 s; unsigned u[4]; } af;
            af.u[0] = pack_bf2(al.x, al.y);
            af.u[1] = pack_bf2(al.z, al.w);
            af.u[2] = pack_bf2(ah.x, ah.y);
            af.u[3] = pack_bf2(ah.z, ah.w);
            acc0 = __builtin_amdgcn_mfma_f32_16x16x32_bf16(af.s, b0, acc0, 0, 0, 0);
            acc1 = __builtin_amdgcn_mfma_f32_16x16x32_bf16(af.s, b1, acc1, 0, 0, 0);
        }
    }

    // ---- in-kernel cross-wave reduction: 8 partials -> z[16][32] ----------
    __syncthreads();                   // all tile reads done; reuse smem
    float* red = reinterpret_cast<float*>(smem);   // [8][16][32] = 16 KB
    {
        // C layout: batch-row = kg*4 + j, r = lane&15 (acc0) / 16+(lane&15) (acc1)
        float* rw = red + w * (ROWS * RDIM);
        #pragma unroll
        for (int j = 0; j < 4; ++j) {
            rw[(kg * 4 + j) * RDIM + m]      = acc0[j];
            rw[(kg * 4 + j) * RDIM + 16 + m] = acc1[j];
        }
    }
    __syncthreads();
    {
        const int e = tid;             // 512 = 16 rows x 32 r exactly
        float s = 0.f;
        #pragma unroll
        for (int ww = 0; ww < 8; ++ww) s += red[ww * (ROWS * RDIM) + e];
        z[(size_t)(brow + (e >> 5)) * RDIM + (e & 31)] = s;
    }
}

// ---- phase B: y[b][j] = sum_r z[b][r] * U[j][r] ---------------------------
#define TJ 256
#define TB 64

__global__ __launch_bounds__(256) void ykernel(
    const float* __restrict__ z, const float* __restrict__ U,
    float* __restrict__ y)
{
    const int j  = blockIdx.x * TJ + threadIdx.x;
    const int b0 = blockIdx.y * TB;

    float u[RDIM];
    #pragma unroll
    for (int q = 0; q < 8; ++q) {
        const float4 v = *reinterpret_cast<const float4*>(&U[(size_t)j * RDIM + q * 4]);
        u[q * 4 + 0] = v.x; u[q * 4 + 1] = v.y; u[q * 4 + 2] = v.z; u[q * 4 + 3] = v.w;
    }

    for (int bb = 0; bb < TB; ++bb) {
        const float* zr = &z[(size_t)(b0 + bb) * RDIM];
        float a0 = 0.f, a1 = 0.f, a2 = 0.f, a3 = 0.f;
        #pragma unroll
        for (int r = 0; r < RDIM; r += 4) {
            a0 += zr[r + 0] * u[r + 0];
            a1 += zr[r + 1] * u[r + 1];
            a2 += zr[r + 2] * u[r + 2];
            a3 += zr[r + 3] * u[r + 3];
        }
        // NT store: y is write-once; keep it OUT of L3 so next replay's zpart
        // reads hit a clean L3 (no DRAM read/writeback turnaround thrash).
        __builtin_nontemporal_store((a0 + a1) + (a2 + a3),
                                    &y[(size_t)(b0 + bb) * NPOST + j]);
    }
}

extern "C" void kernel_launch(void* const* d_in, const int* in_sizes, int n_in,
                              void* d_out, int out_size, void* d_ws, size_t ws_size,
                              hipStream_t stream)
{
    const float* spikes = (const float*)d_in[0];   // [4096, 16384]
    const float* U      = (const float*)d_in[1];   // [16384, 32]
    const float* V      = (const float*)d_in[2];   // [16384, 32]

    float* y     = (float*)d_out;
    short* vpack = (short*)d_out;      // 1 MB at front of d_out; consumed by zpart
                                       // before ykernel overwrites with y
    float* z     = (float*)d_ws;       // 512 KB

    vpack_kernel<<<256, 256, 0, stream>>>(V, vpack);
    zpart_kernel<<<B_DIM / ROWS, 512, 0, stream>>>(spikes, vpack, z);
    ykernel<<<dim3(NPOST / TJ, B_DIM / TB), 256, 0, stream>>>(z, U, y);
}

// Round 11
// 158.419 us; speedup vs baseline: 1.0832x; 1.0832x over previous
//
#include <hip/hip_runtime.h>
#include <hip/hip_bf16.h>

// y = (spikes @ V) @ U^T
// spikes: [4096, 16384] f32, V: [16384, 32] f32, U: [16384, 32] f32
// y: [4096, 16384] f32 (268 MB). Mask inputs are dead in the reference.
//
// r11: T3+T4 counted-vmcnt deep pipeline. r9's structure drained vmcnt to 0
// every tile (convoy bursts, ~40% duty) -> 2.35 TB/s. Here: 4 LDS buffers,
// 4x1KB DMA per tile per wave (A rows + B fragments both through the DMA
// stream so vmcnt counting stays exact), loop waits vmcnt(8) (2 tiles in
// flight ALWAYS), raw s_barrier, vmcnt(0) only in the 3-iter epilogue.
// Sustained outstanding ~64-96 KB/CU >> Little's-law need (~10 KB/CU).

#define B_DIM 4096
#define NPRE  16384
#define NPOST 16384
#define RDIM  32

#define ROWS   16
#define TILEK  256                   // k per tile (1 KB per row)
#define NTILE  (NPRE / TILEK)        // 64
#define ABYTES 16384                 // A region: 16 rows x 1024 B
#define BUFB   32768                 // A (16 KB) + B (16 KB) per buffer
// smem = 4 * BUFB = 128 KB (m201-validated size) -> 1 block/CU

typedef __attribute__((ext_vector_type(8))) short short8;   // 8 bf16
typedef __attribute__((ext_vector_type(4))) float f32x4;
typedef const __attribute__((address_space(1))) void GAS;
typedef __attribute__((address_space(3))) void LAS;

static __device__ __forceinline__ unsigned pack_bf2(float lo, float hi) {
    union { __hip_bfloat162 h; unsigned u; } c;
    c.h = __float22bfloat162_rn(make_float2(lo, hi));   // v_cvt_pk_bf16_f32
    return c.u;
}

// ---- V packing (proven r4): vpack[((kt*2+half)*64 + lane)*8 + e]
//      = bf16(V[kt*32 + (lane>>4)*8 + e][half*16 + (lane&15)])
__global__ void vpack_kernel(const float* __restrict__ V, short* __restrict__ vpack)
{
    const int tid  = blockIdx.x * 256 + threadIdx.x;   // 65536
    const int lane = tid & 63;
    const int half = (tid >> 6) & 1;
    const int kt   = tid >> 7;
    const int n    = half * 16 + (lane & 15);
    const int k0   = kt * 32 + (lane >> 4) * 8;
    union { short8 s; short el[8]; } f;
    #pragma unroll
    for (int e = 0; e < 8; ++e) {
        union { __hip_bfloat16 h; short s; } c;
        c.h = __float2bfloat16(V[(size_t)(k0 + e) * RDIM + n]);
        f.el[e] = c.s;
    }
    *reinterpret_cast<short8*>(vpack + (size_t)tid * 8) = f.s;
}

// ---- phase A: block = 16 rows x full K; wave w owns kstep w of each tile --
__global__ __launch_bounds__(512) void zpart_kernel(
    const float* __restrict__ spikes, const short* __restrict__ vpack,
    float* __restrict__ z)
{
    __shared__ char smem[4 * BUFB];    // 128 KB

    const int tid  = threadIdx.x;
    const int lane = tid & 63;
    const int w    = tid >> 6;         // wave 0..7
    const int brow = blockIdx.x * ROWS;

    const int m  = lane & 15;          // fragment batch-row
    const int kg = lane >> 4;          // k-group
    const int m7 = m & 7;

    // --- DMA descriptors (4 x 1KB per tile per wave) ---
    // A: rows 2w, 2w+1; source granule-XOR-swizzled (rule 21): LDS stays
    // linear, global src granule = (l&~7)|((l&7)^(row&7)).
    const float* ga0; const float* ga1;
    {
        const int r0 = 2 * w, r1 = 2 * w + 1;
        const int l0 = (lane & ~7) | ((lane & 7) ^ (r0 & 7));
        const int l1 = (lane & ~7) | ((lane & 7) ^ (r1 & 7));
        ga0 = spikes + (size_t)(brow + r0) * NPRE + l0 * 4;
        ga1 = spikes + (size_t)(brow + r1) * NPRE + l1 * 4;
    }
    const int laA0 = (2 * w) * 1024, laA1 = (2 * w + 1) * 1024;
    // B: pieces 2w, 2w+1 (kstep w, halves 0/1); global piece = t*16 + piece
    const short* gb0 = vpack + (size_t)(2 * w) * 512 + lane * 8;
    const short* gb1 = vpack + (size_t)(2 * w + 1) * 512 + lane * 8;
    const int laB0 = ABYTES + (2 * w) * 1024, laB1 = ABYTES + (2 * w + 1) * 1024;

    // --- compute descriptors (constant per thread) ---
    const int offA0 = m * 1024 + ((w << 3) + ((2 * kg) ^ m7)) * 16;
    const int offA1 = m * 1024 + ((w << 3) + ((2 * kg + 1) ^ m7)) * 16;
    const int offB0 = ABYTES + (2 * w) * 1024 + lane * 16;
    const int offB1 = offB0 + 1024;

    f32x4 acc0 = {0.f, 0.f, 0.f, 0.f};
    f32x4 acc1 = {0.f, 0.f, 0.f, 0.f};

#define STAGE(T) do {                                                         \
        char* base_ = smem + (((T) & 3) * BUFB);                              \
        __builtin_amdgcn_global_load_lds((GAS*)(gb0 + (size_t)(T) * 8192),    \
                                         (LAS*)(base_ + laB0), 16, 0, 0);     \
        __builtin_amdgcn_global_load_lds((GAS*)(gb1 + (size_t)(T) * 8192),    \
                                         (LAS*)(base_ + laB1), 16, 0, 0);     \
        __builtin_amdgcn_global_load_lds((GAS*)(ga0 + (size_t)(T) * TILEK),   \
                                         (LAS*)(base_ + laA0), 16, 0, 0);     \
        __builtin_amdgcn_global_load_lds((GAS*)(ga1 + (size_t)(T) * TILEK),   \
                                         (LAS*)(base_ + laA1), 16, 0, 0);     \
    } while (0)

#define COMPUTE(T) do {                                                       \
        const char* ab_ = smem + (((T) & 3) * BUFB);                          \
        const f32x4 al = *reinterpret_cast<const f32x4*>(ab_ + offA0);        \
        const f32x4 ah = *reinterpret_cast<const f32x4*>(ab_ + offA1);        \
        const short8 b0 = *reinterpret_cast<const short8*>(ab_ + offB0);      \
        const short8 b1 = *reinterpret_cast<const short8*>(ab_ + offB1);      \
        union { short8 s; unsigned u[4]; } af;                                \
        af.u[0] = pack_bf2(al.x, al.y);                                       \
        af.u[1] = pack_bf2(al.z, al.w);                                       \
        af.u[2] = pack_bf2(ah.x, ah.y);                                       \
        af.u[3] = pack_bf2(ah.z, ah.w);                                       \
        acc0 = __builtin_amdgcn_mfma_f32_16x16x32_bf16(af.s, b0, acc0, 0, 0, 0); \
        acc1 = __builtin_amdgcn_mfma_f32_16x16x32_bf16(af.s, b1, acc1, 0, 0, 0); \
    } while (0)

    // prologue: 3 tiles in flight (12 loads/wave)
    STAGE(0); STAGE(1); STAGE(2);

    #pragma unroll 1
    for (int t = 0; t < NTILE - 3; ++t) {
        asm volatile("s_waitcnt vmcnt(8)" ::: "memory");   // tile t landed (own 4)
        __builtin_amdgcn_s_barrier();                      // all waves' tile t landed
        __builtin_amdgcn_sched_barrier(0);                 // pin: no hoist across wait
        STAGE(t + 3);                                      // refill; never drain to 0
        COMPUTE(t);
    }
    // epilogue: drain 8 -> 4 -> 0
    asm volatile("s_waitcnt vmcnt(8)" ::: "memory");
    __builtin_amdgcn_s_barrier();
    __builtin_amdgcn_sched_barrier(0);
    COMPUTE(NTILE - 3);
    asm volatile("s_waitcnt vmcnt(4)" ::: "memory");
    __builtin_amdgcn_s_barrier();
    __builtin_amdgcn_sched_barrier(0);
    COMPUTE(NTILE - 2);
    asm volatile("s_waitcnt vmcnt(0)" ::: "memory");
    __builtin_amdgcn_s_barrier();
    __builtin_amdgcn_sched_barrier(0);
    COMPUTE(NTILE - 1);

#undef STAGE
#undef COMPUTE

    // ---- in-kernel cross-wave reduction: 8 partials -> z[16][32] (r9) -----
    __syncthreads();
    float* red = reinterpret_cast<float*>(smem);   // [8][16][32] = 16 KB
    {
        float* rw = red + w * (ROWS * RDIM);
        #pragma unroll
        for (int j = 0; j < 4; ++j) {
            rw[(kg * 4 + j) * RDIM + m]      = acc0[j];
            rw[(kg * 4 + j) * RDIM + 16 + m] = acc1[j];
        }
    }
    __syncthreads();
    {
        const int e = tid;             // 512 = 16 rows x 32 r exactly
        float s = 0.f;
        #pragma unroll
        for (int ww = 0; ww < 8; ++ww) s += red[ww * (ROWS * RDIM) + e];
        z[(size_t)(brow + (e >> 5)) * RDIM + (e & 31)] = s;
    }
}

// ---- phase B: y[b][j] = sum_r z[b][r] * U[j][r] ---------------------------
#define TJ 256
#define TB 64

__global__ __launch_bounds__(256) void ykernel(
    const float* __restrict__ z, const float* __restrict__ U,
    float* __restrict__ y)
{
    const int j  = blockIdx.x * TJ + threadIdx.x;
    const int b0 = blockIdx.y * TB;

    float u[RDIM];
    #pragma unroll
    for (int q = 0; q < 8; ++q) {
        const float4 v = *reinterpret_cast<const float4*>(&U[(size_t)j * RDIM + q * 4]);
        u[q * 4 + 0] = v.x; u[q * 4 + 1] = v.y; u[q * 4 + 2] = v.z; u[q * 4 + 3] = v.w;
    }

    for (int bb = 0; bb < TB; ++bb) {
        const float* zr = &z[(size_t)(b0 + bb) * RDIM];
        float a0 = 0.f, a1 = 0.f, a2 = 0.f, a3 = 0.f;
        #pragma unroll
        for (int r = 0; r < RDIM; r += 4) {
            a0 += zr[r + 0] * u[r + 0];
            a1 += zr[r + 1] * u[r + 1];
            a2 += zr[r + 2] * u[r + 2];
            a3 += zr[r + 3] * u[r + 3];
        }
        y[(size_t)(b0 + bb) * NPOST + j] = (a0 + a1) + (a2 + a3);
    }
}

extern "C" void kernel_launch(void* const* d_in, const int* in_sizes, int n_in,
                              void* d_out, int out_size, void* d_ws, size_t ws_size,
                              hipStream_t stream)
{
    const float* spikes = (const float*)d_in[0];   // [4096, 16384]
    const float* U      = (const float*)d_in[1];   // [16384, 32]
    const float* V      = (const float*)d_in[2];   // [16384, 32]

    float* y     = (float*)d_out;
    short* vpack = (short*)d_out;      // 1 MB at front of d_out; fully consumed
                                       // by zpart before ykernel overwrites
    float* z     = (float*)d_ws;       // 512 KB

    vpack_kernel<<<256, 256, 0, stream>>>(V, vpack);
    zpart_kernel<<<B_DIM / ROWS, 512, 0, stream>>>(spikes, vpack, z);
    ykernel<<<dim3(NPOST / TJ, B_DIM / TB), 256, 0, stream>>>(z, U, y);
}